// Round 10
// baseline (10883.064 us; speedup 1.0000x reference)
//
#include <hip/hip_runtime.h>
#include <cmath>

#define B_ 32
#define T_ 512
#define W_ 250
#define D_ 768
#define H_ 768
#define G_ 3072   // 4*H
#define NT_ 2

#define NBAR_ 2112   // barrier area (512-variant): 16 grp lines (64 uints apart) + root + 16 go lines
                     // (256-variant uses a subset layout; only one variant runs per execution)

// ============================ first-subtoken gather ============================
__global__ void first_idx_kernel(const int* __restrict__ words_ids, int* __restrict__ fidx,
                                 unsigned int* __restrict__ counter) {
  int i = blockIdx.x * blockDim.x + threadIdx.x;
  if (i < NBAR_) counter[i] = 0u;  // zero the whole barrier area
  if (i >= B_ * W_) return;
  int b = i / W_, w = i % W_;
  const int* row = words_ids + (size_t)b * T_;
  int idx = T_ - 1;
  for (int t = 0; t < T_; ++t) {
    if (row[t] == w) { idx = t; break; }
  }
  fidx[i] = idx;
}

// feat layout: [W][B][D]  (time-major so a time-chunk is contiguous GEMM rows)
__global__ void gather_kernel(const float* __restrict__ bert_out, const int* __restrict__ fidx,
                              float* __restrict__ feat) {
  int i = blockIdx.x * blockDim.x + threadIdx.x;
  const int nv = D_ / 4;
  if (i >= B_ * W_ * nv) return;
  int bw = i / nv, d4 = i % nv;
  int b = bw / W_, w = bw % W_;
  int t = fidx[bw];
  float4 v = ((const float4*)(bert_out + ((size_t)b * T_ + t) * D_))[d4];
  ((float4*)(feat + ((size_t)w * B_ + b) * D_))[d4] = v;
}

// ============================ fp32 GEMM: C[M,N] = A[M,K] * B[N,K]^T + bias[N] ============================
__global__ __launch_bounds__(256) void gemm_bias_kernel(
    const float* __restrict__ A, const float* __restrict__ Bm,
    const float* __restrict__ bias, float* __restrict__ C,
    int M, int N, int K) {
  __shared__ float As[2][16][132];
  __shared__ float Bs[2][16][132];
  const int tid = threadIdx.x;
  const int row0 = blockIdx.x * 128;
  const int col0 = blockIdx.y * 128;
  const int tx = tid & 15;       // N dim of microtile
  const int ty = tid >> 4;       // M dim of microtile
  const int lr = tid >> 1;       // 0..127 : tile row this thread loads
  const int lk = (tid & 1) * 8;  // k offset 0 or 8

  int ar = row0 + lr;
  if (ar >= M) ar = M - 1;                 // clamp (results of padded rows never stored)
  const float* __restrict__ Ap = A + (size_t)ar * K + lk;
  const float* __restrict__ Bp = Bm + (size_t)(col0 + lr) * K + lk;

  float acc[8][8];
#pragma unroll
  for (int i = 0; i < 8; ++i)
#pragma unroll
    for (int j = 0; j < 8; ++j) acc[i][j] = 0.0f;

  const int nk = K >> 4;

  {
    float4 a0 = *(const float4*)(Ap + 0);
    float4 a1 = *(const float4*)(Ap + 4);
    float4 b0 = *(const float4*)(Bp + 0);
    float4 b1 = *(const float4*)(Bp + 4);
    As[0][lk + 0][lr] = a0.x; As[0][lk + 1][lr] = a0.y; As[0][lk + 2][lr] = a0.z; As[0][lk + 3][lr] = a0.w;
    As[0][lk + 4][lr] = a1.x; As[0][lk + 5][lr] = a1.y; As[0][lk + 6][lr] = a1.z; As[0][lk + 7][lr] = a1.w;
    Bs[0][lk + 0][lr] = b0.x; Bs[0][lk + 1][lr] = b0.y; Bs[0][lk + 2][lr] = b0.z; Bs[0][lk + 3][lr] = b0.w;
    Bs[0][lk + 4][lr] = b1.x; Bs[0][lk + 5][lr] = b1.y; Bs[0][lk + 6][lr] = b1.z; Bs[0][lk + 7][lr] = b1.w;
  }
  __syncthreads();

  for (int t = 0; t < nk; ++t) {
    const int cur = t & 1;
    float4 a0, a1, b0, b1;
    const bool pf = (t + 1 < nk);
    if (pf) {
      const int k0 = (t + 1) << 4;
      a0 = *(const float4*)(Ap + k0);
      a1 = *(const float4*)(Ap + k0 + 4);
      b0 = *(const float4*)(Bp + k0);
      b1 = *(const float4*)(Bp + k0 + 4);
    }
#pragma unroll
    for (int k = 0; k < 16; ++k) {
      float a[8], b[8];
      *(float4*)&a[0] = *(const float4*)&As[cur][k][ty * 8];
      *(float4*)&a[4] = *(const float4*)&As[cur][k][ty * 8 + 4];
      *(float4*)&b[0] = *(const float4*)&Bs[cur][k][tx * 8];
      *(float4*)&b[4] = *(const float4*)&Bs[cur][k][tx * 8 + 4];
#pragma unroll
      for (int i = 0; i < 8; ++i)
#pragma unroll
        for (int j = 0; j < 8; ++j) acc[i][j] += a[i] * b[j];
    }
    if (pf) {
      const int nxt = cur ^ 1;
      As[nxt][lk + 0][lr] = a0.x; As[nxt][lk + 1][lr] = a0.y; As[nxt][lk + 2][lr] = a0.z; As[nxt][lk + 3][lr] = a0.w;
      As[nxt][lk + 4][lr] = a1.x; As[nxt][lk + 5][lr] = a1.y; As[nxt][lk + 6][lr] = a1.z; As[nxt][lk + 7][lr] = a1.w;
      Bs[nxt][lk + 0][lr] = b0.x; Bs[nxt][lk + 1][lr] = b0.y; Bs[nxt][lk + 2][lr] = b0.z; Bs[nxt][lk + 3][lr] = b0.w;
      Bs[nxt][lk + 4][lr] = b1.x; Bs[nxt][lk + 5][lr] = b1.y; Bs[nxt][lk + 6][lr] = b1.z; Bs[nxt][lk + 7][lr] = b1.w;
    }
    __syncthreads();
  }

#pragma unroll
  for (int i = 0; i < 8; ++i) {
    int r = row0 + ty * 8 + i;
    if (r < M) {
#pragma unroll
      for (int j = 0; j < 8; ++j) {
        int c = col0 + tx * 8 + j;
        C[(size_t)r * N + c] = acc[i][j] + bias[c];
      }
    }
  }
}

// ============================ BiLSTM recurrence: PERSISTENT, 256 blocks (r9, proven) ============================
// Fallback variant. 256 blocks x 6 units, 1 block/CU. Identical to round 9's passing kernel.
__global__ __launch_bounds__(256) void lstm_persist_kernel(
    const float* __restrict__ pre_f, const float* __restrict__ pre_r,
    const float* __restrict__ whh_f, const float* __restrict__ whh_r,
    float* __restrict__ out, float* __restrict__ hbuf, float* __restrict__ cbuf,
    unsigned int* __restrict__ counter, int s0, int Cc, int ep0) {
  const int wg = blockIdx.x;
  const int dir = wg >> 7;
  const int lw = wg & 127;
  const float* __restrict__ pre = dir ? pre_r : pre_f;
  const float* __restrict__ whh = dir ? whh_r : whh_f;
  float* hb = hbuf + (size_t)dir * 2 * B_ * H_;
  float* cb = cbuf + (size_t)dir * B_ * H_;
  const int tid = threadIdx.x;
  const int u0 = lw * 6;

  const int rgrp = tid >> 6;
  const int lane = tid & 63;
  const int kgrp = lane >> 3;
  const int bgrp = lane & 7;

  __shared__ float w_lds[24 * 860];
  __shared__ float h_lds[32 * 284];
  __shared__ float g_lds[32][24];

  unsigned int* __restrict__ grp  = counter + ((wg & 7) << 6);
  unsigned int* __restrict__ root = counter + 512;
  unsigned int* __restrict__ gow  = counter + 576 + ((wg & 7) << 6);

#pragma unroll
  for (int v = 0; v < 18; ++v) {
    int i = v * 256 + tid;
    int r24 = i / 192;
    int f4 = i - r24 * 192;
    int k = f4 * 4;
    int grow = (r24 / 6) * H_ + u0 + (r24 % 6);
    *(float4*)&w_lds[r24 * 860 + k + 4 * (k >> 5)] =
        *(const float4*)(whh + (size_t)grow * H_ + k);
  }

  const int cui = tid >> 5;
  const int cb_ = tid & 31;
  float creg = 0.0f;
  if (tid < 192 && s0 > 0) creg = cb[(size_t)cb_ * H_ + u0 + cui];

  float pre_g0 = 0.f, pre_g1 = 0.f, pre_g2 = 0.f, pre_g3 = 0.f;
  if (tid < 192) {
    const int prow0 = dir ? (Cc - 1) : 0;
    const float* pbt = pre + ((size_t)prow0 * B_ + cb_) * G_;
    pre_g0 = pbt[0 * H_ + u0 + cui];
    pre_g1 = pbt[1 * H_ + u0 + cui];
    pre_g2 = pbt[2 * H_ + u0 + cui];
    pre_g3 = pbt[3 * H_ + u0 + cui];
  }

  const int kl0 = kgrp * 32;

  for (int sl = 0; sl < Cc; ++sl) {
    const int s = s0 + sl;
    const int w = dir ? (W_ - 1 - s) : s;

    float acc[6][4];
#pragma unroll
    for (int r = 0; r < 6; ++r)
#pragma unroll
      for (int j = 0; j < 4; ++j) acc[r][j] = 0.0f;

    if (s > 0) {
      const float* __restrict__ hprev = hb + (size_t)(s & 1) * B_ * H_;

      unsigned long long hq[16];
#pragma unroll
      for (int v = 0; v < 8; ++v) {
        int e = v * 1024 + tid * 4;
        int bb = e >> 8;
        int kk = e & 255;
        const unsigned long long* src =
            (const unsigned long long*)(hprev + (size_t)bb * H_ + kk);
        hq[2 * v]     = __hip_atomic_load(src + 0, __ATOMIC_RELAXED, __HIP_MEMORY_SCOPE_AGENT);
        hq[2 * v + 1] = __hip_atomic_load(src + 1, __ATOMIC_RELAXED, __HIP_MEMORY_SCOPE_AGENT);
      }

      for (int kc = 0; kc < H_; kc += 256) {
        __syncthreads();
#pragma unroll
        for (int v = 0; v < 8; ++v) {
          int e = v * 1024 + tid * 4;
          int bb = e >> 8;
          int kk = e & 255;
          int off = bb * 284 + kk + 4 * (kk >> 5);
          union { unsigned long long u; float f[2]; } q0, q1;
          q0.u = hq[2 * v]; q1.u = hq[2 * v + 1];
          h_lds[off + 0] = q0.f[0]; h_lds[off + 1] = q0.f[1];
          h_lds[off + 2] = q1.f[0]; h_lds[off + 3] = q1.f[1];
        }
        __syncthreads();
        if (kc + 256 < H_) {
#pragma unroll
          for (int v = 0; v < 8; ++v) {
            int e = v * 1024 + tid * 4;
            int bb = e >> 8;
            int kk = e & 255;
            const unsigned long long* src =
                (const unsigned long long*)(hprev + (size_t)bb * H_ + kc + 256 + kk);
            hq[2 * v]     = __hip_atomic_load(src + 0, __ATOMIC_RELAXED, __HIP_MEMORY_SCOPE_AGENT);
            hq[2 * v + 1] = __hip_atomic_load(src + 1, __ATOMIC_RELAXED, __HIP_MEMORY_SCOPE_AGENT);
          }
        }

        const int wbase = kc + kl0;
#pragma unroll 4
        for (int t = 0; t < 8; ++t) {
          const int kl = kl0 + t * 4;
          const int ka = wbase + t * 4;
          const int hoff = kl + 4 * (kl >> 5);
          const int woff = ka + 4 * (ka >> 5);
          float4 h4_0 = *(const float4*)&h_lds[(4 * bgrp + 0) * 284 + hoff];
          float4 h4_1 = *(const float4*)&h_lds[(4 * bgrp + 1) * 284 + hoff];
          float4 h4_2 = *(const float4*)&h_lds[(4 * bgrp + 2) * 284 + hoff];
          float4 h4_3 = *(const float4*)&h_lds[(4 * bgrp + 3) * 284 + hoff];
#pragma unroll
          for (int r = 0; r < 6; ++r) {
            float4 w4 = *(const float4*)&w_lds[(rgrp * 6 + r) * 860 + woff];
            acc[r][0] += h4_0.x * w4.x + h4_0.y * w4.y + h4_0.z * w4.z + h4_0.w * w4.w;
            acc[r][1] += h4_1.x * w4.x + h4_1.y * w4.y + h4_1.z * w4.z + h4_1.w * w4.w;
            acc[r][2] += h4_2.x * w4.x + h4_2.y * w4.y + h4_2.z * w4.z + h4_2.w * w4.w;
            acc[r][3] += h4_3.x * w4.x + h4_3.y * w4.y + h4_3.z * w4.z + h4_3.w * w4.w;
          }
        }
      }

#pragma unroll
      for (int r = 0; r < 6; ++r)
#pragma unroll
        for (int j = 0; j < 4; ++j) {
          float a = acc[r][j];
          a += __shfl_xor(a, 8, 64);
          a += __shfl_xor(a, 16, 64);
          a += __shfl_xor(a, 32, 64);
          acc[r][j] = a;
        }
      if (kgrp == 0) {
#pragma unroll
        for (int r = 0; r < 6; ++r)
#pragma unroll
          for (int j = 0; j < 4; ++j)
            g_lds[4 * bgrp + j][rgrp * 6 + r] = acc[r][j];
      }
    }

    __syncthreads();

    if (tid < 192) {
      float gi = pre_g0, gf = pre_g1, gg = pre_g2, go = pre_g3;
      if (s > 0) {
        gi += g_lds[cb_][cui];
        gf += g_lds[cb_][6 + cui];
        gg += g_lds[cb_][12 + cui];
        go += g_lds[cb_][18 + cui];
      }
      const float si = 1.0f / (1.0f + expf(-gi));
      const float sf = 1.0f / (1.0f + expf(-gf));
      const float so = 1.0f / (1.0f + expf(-go));
      creg = sf * creg + si * tanhf(gg);
      const float h = so * tanhf(creg);
      float* __restrict__ hnext = hb + (size_t)((s + 1) & 1) * B_ * H_;
      __hip_atomic_store(&hnext[(size_t)cb_ * H_ + u0 + cui], h,
                         __ATOMIC_RELAXED, __HIP_MEMORY_SCOPE_AGENT);
      out[((size_t)w * B_ + cb_) * (2 * H_) + (size_t)dir * H_ + u0 + cui] = h;
      if (sl + 1 < Cc) {
        const int prown = dir ? (Cc - 2 - sl) : (sl + 1);
        const float* pbtn = pre + ((size_t)prown * B_ + cb_) * G_;
        pre_g0 = pbtn[0 * H_ + u0 + cui];
        pre_g1 = pbtn[1 * H_ + u0 + cui];
        pre_g2 = pbtn[2 * H_ + u0 + cui];
        pre_g3 = pbtn[3 * H_ + u0 + cui];
      }
    }

    __syncthreads();
    if (tid == 0) {
      const unsigned int ep1 = (unsigned int)(ep0 + sl + 1);
      unsigned int old = __hip_atomic_fetch_add(grp, 1u, __ATOMIC_RELAXED, __HIP_MEMORY_SCOPE_AGENT);
      if (old == 32u * ep1 - 1u) {
        __hip_atomic_fetch_add(root, 1u, __ATOMIC_RELAXED, __HIP_MEMORY_SCOPE_AGENT);
        while (__hip_atomic_load(root, __ATOMIC_RELAXED, __HIP_MEMORY_SCOPE_AGENT) < 8u * ep1) {
          __builtin_amdgcn_s_sleep(2);
        }
        __hip_atomic_store(gow, ep1, __ATOMIC_RELAXED, __HIP_MEMORY_SCOPE_AGENT);
      } else {
        while (__hip_atomic_load(gow, __ATOMIC_RELAXED, __HIP_MEMORY_SCOPE_AGENT) < ep1) {
          __builtin_amdgcn_s_sleep(2);
        }
      }
    }
    __syncthreads();
  }

  if (tid < 192) cb[(size_t)cb_ * H_ + u0 + cui] = creg;
}

// ============================ BiLSTM recurrence: PERSISTENT, 512 blocks / 2 per CU ============================
// ROUND 10: 512 blocks (256/dir), 3 units/block (12 gate rows). LDS 79.2 KB ->
// 2 blocks/CU: the co-resident block's waves hide this block's LDS/L3 stalls and
// barrier-arrival jitter (r9 was 1 wave/SIMD, everything exposed). Lane math is
// round-5's verbatim (passed, absmax 0.0); h staging + pre prefetch are round-9's
// verbatim; barrier is round-7's proven algorithm with 16 groups x 32 blocks
// (same per-line contention). Host falls back to the 256-block kernel if the
// occupancy query reports < 2 blocks/CU (cannot hang on failed co-residency).
__global__ __launch_bounds__(256) void lstm_persist512_kernel(
    const float* __restrict__ pre_f, const float* __restrict__ pre_r,
    const float* __restrict__ whh_f, const float* __restrict__ whh_r,
    float* __restrict__ out, float* __restrict__ hbuf, float* __restrict__ cbuf,
    unsigned int* __restrict__ counter, int s0, int Cc, int ep0) {
  const int wg = blockIdx.x;
  const int dir = wg >> 8;         // 512 blocks: 256 per direction
  const int lw = wg & 255;
  const float* __restrict__ pre = dir ? pre_r : pre_f;
  const float* __restrict__ whh = dir ? whh_r : whh_f;
  float* hb = hbuf + (size_t)dir * 2 * B_ * H_;
  float* cb = cbuf + (size_t)dir * B_ * H_;
  const int tid = threadIdx.x;
  const int u0 = lw * 3;           // 3 units per block

  const int rgrp = tid >> 6;       // wave index == gate 0..3
  const int lane = tid & 63;
  const int kgrp = lane >> 3;      // 0..7 : k-split
  const int bgrp = lane & 7;       // 0..7 : batch quad

  __shared__ float w_lds[12 * 860];   // 41280 B, skewed: this block's 12 gate rows
  __shared__ float h_lds[32 * 284];   // 36352 B, skewed, one 256-k chunk
  __shared__ float g_lds[32][12];     // 1536 B

  // barrier lines: 16 groups x 32 blocks; root at 1024; go lines at 1088+
  unsigned int* __restrict__ grp  = counter + ((wg & 15) << 6);
  unsigned int* __restrict__ root = counter + 1024;
  unsigned int* __restrict__ gow  = counter + 1088 + ((wg & 15) << 6);

  // ---- stage 12 weight rows into skewed LDS ONCE (2304 float4, 9/thread) ----
#pragma unroll
  for (int v = 0; v < 9; ++v) {
    int i = v * 256 + tid;          // 0..2303
    int r12 = i / 192;              // 0..11
    int f4 = i - r12 * 192;         // 0..191
    int k = f4 * 4;
    int grow = (r12 / 3) * H_ + u0 + (r12 % 3);
    *(float4*)&w_lds[r12 * 860 + k + 4 * (k >> 5)] =
        *(const float4*)(whh + (size_t)grow * H_ + k);
  }

  // combine-thread ownership: tid<96 owns (batch cb_, unit cui); c kept in register
  const int cui = tid >> 5;        // 0..2 valid when tid < 96
  const int cb_ = tid & 31;
  float creg = 0.0f;
  if (tid < 96 && s0 > 0) creg = cb[(size_t)cb_ * H_ + u0 + cui];

  float pre_g0 = 0.f, pre_g1 = 0.f, pre_g2 = 0.f, pre_g3 = 0.f;
  if (tid < 96) {
    const int prow0 = dir ? (Cc - 1) : 0;
    const float* pbt = pre + ((size_t)prow0 * B_ + cb_) * G_;
    pre_g0 = pbt[0 * H_ + u0 + cui];
    pre_g1 = pbt[1 * H_ + u0 + cui];
    pre_g2 = pbt[2 * H_ + u0 + cui];
    pre_g3 = pbt[3 * H_ + u0 + cui];
  }

  const int kl0 = kgrp * 32;

  for (int sl = 0; sl < Cc; ++sl) {
    const int s = s0 + sl;
    const int w = dir ? (W_ - 1 - s) : s;

    float acc[3][4];
#pragma unroll
    for (int r = 0; r < 3; ++r)
#pragma unroll
      for (int j = 0; j < 4; ++j) acc[r][j] = 0.0f;

    if (s > 0) {
      const float* __restrict__ hprev = hb + (size_t)(s & 1) * B_ * H_;

      unsigned long long hq[16];
#pragma unroll
      for (int v = 0; v < 8; ++v) {
        int e = v * 1024 + tid * 4;
        int bb = e >> 8;
        int kk = e & 255;
        const unsigned long long* src =
            (const unsigned long long*)(hprev + (size_t)bb * H_ + kk);
        hq[2 * v]     = __hip_atomic_load(src + 0, __ATOMIC_RELAXED, __HIP_MEMORY_SCOPE_AGENT);
        hq[2 * v + 1] = __hip_atomic_load(src + 1, __ATOMIC_RELAXED, __HIP_MEMORY_SCOPE_AGENT);
      }

      for (int kc = 0; kc < H_; kc += 256) {
        __syncthreads();
#pragma unroll
        for (int v = 0; v < 8; ++v) {
          int e = v * 1024 + tid * 4;
          int bb = e >> 8;
          int kk = e & 255;
          int off = bb * 284 + kk + 4 * (kk >> 5);
          union { unsigned long long u; float f[2]; } q0, q1;
          q0.u = hq[2 * v]; q1.u = hq[2 * v + 1];
          h_lds[off + 0] = q0.f[0]; h_lds[off + 1] = q0.f[1];
          h_lds[off + 2] = q1.f[0]; h_lds[off + 3] = q1.f[1];
        }
        __syncthreads();
        if (kc + 256 < H_) {
#pragma unroll
          for (int v = 0; v < 8; ++v) {
            int e = v * 1024 + tid * 4;
            int bb = e >> 8;
            int kk = e & 255;
            const unsigned long long* src =
                (const unsigned long long*)(hprev + (size_t)bb * H_ + kc + 256 + kk);
            hq[2 * v]     = __hip_atomic_load(src + 0, __ATOMIC_RELAXED, __HIP_MEMORY_SCOPE_AGENT);
            hq[2 * v + 1] = __hip_atomic_load(src + 1, __ATOMIC_RELAXED, __HIP_MEMORY_SCOPE_AGENT);
          }
        }

        const int wbase = kc + kl0;
#pragma unroll 4
        for (int t = 0; t < 8; ++t) {
          const int kl = kl0 + t * 4;
          const int ka = wbase + t * 4;
          const int hoff = kl + 4 * (kl >> 5);
          const int woff = ka + 4 * (ka >> 5);
          float4 h4_0 = *(const float4*)&h_lds[(4 * bgrp + 0) * 284 + hoff];
          float4 h4_1 = *(const float4*)&h_lds[(4 * bgrp + 1) * 284 + hoff];
          float4 h4_2 = *(const float4*)&h_lds[(4 * bgrp + 2) * 284 + hoff];
          float4 h4_3 = *(const float4*)&h_lds[(4 * bgrp + 3) * 284 + hoff];
#pragma unroll
          for (int r = 0; r < 3; ++r) {
            float4 w4 = *(const float4*)&w_lds[(rgrp * 3 + r) * 860 + woff];
            acc[r][0] += h4_0.x * w4.x + h4_0.y * w4.y + h4_0.z * w4.z + h4_0.w * w4.w;
            acc[r][1] += h4_1.x * w4.x + h4_1.y * w4.y + h4_1.z * w4.z + h4_1.w * w4.w;
            acc[r][2] += h4_2.x * w4.x + h4_2.y * w4.y + h4_2.z * w4.z + h4_2.w * w4.w;
            acc[r][3] += h4_3.x * w4.x + h4_3.y * w4.y + h4_3.z * w4.z + h4_3.w * w4.w;
          }
        }
      }

#pragma unroll
      for (int r = 0; r < 3; ++r)
#pragma unroll
        for (int j = 0; j < 4; ++j) {
          float a = acc[r][j];
          a += __shfl_xor(a, 8, 64);
          a += __shfl_xor(a, 16, 64);
          a += __shfl_xor(a, 32, 64);
          acc[r][j] = a;
        }
      if (kgrp == 0) {
#pragma unroll
        for (int r = 0; r < 3; ++r)
#pragma unroll
          for (int j = 0; j < 4; ++j)
            g_lds[4 * bgrp + j][rgrp * 3 + r] = acc[r][j];
      }
    }

    __syncthreads();

    if (tid < 96) {
      float gi = pre_g0, gf = pre_g1, gg = pre_g2, go = pre_g3;
      if (s > 0) {
        gi += g_lds[cb_][cui];
        gf += g_lds[cb_][3 + cui];
        gg += g_lds[cb_][6 + cui];
        go += g_lds[cb_][9 + cui];
      }
      const float si = 1.0f / (1.0f + expf(-gi));
      const float sf = 1.0f / (1.0f + expf(-gf));
      const float so = 1.0f / (1.0f + expf(-go));
      creg = sf * creg + si * tanhf(gg);
      const float h = so * tanhf(creg);
      float* __restrict__ hnext = hb + (size_t)((s + 1) & 1) * B_ * H_;
      __hip_atomic_store(&hnext[(size_t)cb_ * H_ + u0 + cui], h,
                         __ATOMIC_RELAXED, __HIP_MEMORY_SCOPE_AGENT);
      out[((size_t)w * B_ + cb_) * (2 * H_) + (size_t)dir * H_ + u0 + cui] = h;
      if (sl + 1 < Cc) {
        const int prown = dir ? (Cc - 2 - sl) : (sl + 1);
        const float* pbtn = pre + ((size_t)prown * B_ + cb_) * G_;
        pre_g0 = pbtn[0 * H_ + u0 + cui];
        pre_g1 = pbtn[1 * H_ + u0 + cui];
        pre_g2 = pbtn[2 * H_ + u0 + cui];
        pre_g3 = pbtn[3 * H_ + u0 + cui];
      }
    }

    // ---- two-level grid barrier (r7 algorithm, 16 groups x 32 blocks) ----
    __syncthreads();
    if (tid == 0) {
      const unsigned int ep1 = (unsigned int)(ep0 + sl + 1);
      unsigned int old = __hip_atomic_fetch_add(grp, 1u, __ATOMIC_RELAXED, __HIP_MEMORY_SCOPE_AGENT);
      if (old == 32u * ep1 - 1u) {
        __hip_atomic_fetch_add(root, 1u, __ATOMIC_RELAXED, __HIP_MEMORY_SCOPE_AGENT);
        while (__hip_atomic_load(root, __ATOMIC_RELAXED, __HIP_MEMORY_SCOPE_AGENT) < 16u * ep1) {
          __builtin_amdgcn_s_sleep(2);
        }
        __hip_atomic_store(gow, ep1, __ATOMIC_RELAXED, __HIP_MEMORY_SCOPE_AGENT);
      } else {
        while (__hip_atomic_load(gow, __ATOMIC_RELAXED, __HIP_MEMORY_SCOPE_AGENT) < ep1) {
          __builtin_amdgcn_s_sleep(2);
        }
      }
    }
    __syncthreads();
  }

  if (tid < 96) cb[(size_t)cb_ * H_ + u0 + cui] = creg;
}

// ============================ logits + softmax ============================
// h2 is [W][B][2H]; prob is [B][W][NT]
__global__ void logits_softmax_kernel(const float* __restrict__ h2, const float* __restrict__ w_lin,
                                      const float* __restrict__ b_lin, float* __restrict__ prob) {
  int i = blockIdx.x * blockDim.x + threadIdx.x;
  if (i >= B_ * W_) return;
  int b = i / W_, w = i % W_;
  const float4* x = (const float4*)(h2 + ((size_t)w * B_ + b) * (2 * H_));
  const float4* w0 = (const float4*)(w_lin);
  const float4* w1 = (const float4*)(w_lin + 2 * H_);
  float l0 = 0.f, l1 = 0.f;
#pragma unroll 4
  for (int k = 0; k < (2 * H_) / 4; ++k) {
    float4 xv = x[k];
    float4 a = w0[k];
    float4 c = w1[k];
    l0 += xv.x * a.x + xv.y * a.y + xv.z * a.z + xv.w * a.w;
    l1 += xv.x * c.x + xv.y * c.y + xv.z * c.z + xv.w * c.w;
  }
  l0 += b_lin[0];
  l1 += b_lin[1];
  float m = fmaxf(l0, l1);
  float e0 = expf(l0 - m), e1 = expf(l1 - m);
  float s = e0 + e1;
  prob[2 * (size_t)i] = e0 / s;
  prob[2 * (size_t)i + 1] = e1 / s;
}

// ============================ CRF ============================
__device__ __forceinline__ float lse2(float a, float b) {
  float m = fmaxf(a, b);
  return m + logf(expf(a - m) + expf(b - m));
}

__global__ void crf_llh_kernel(const float* __restrict__ emis, const int* __restrict__ tags,
                               const float* __restrict__ start, const float* __restrict__ endv,
                               const float* __restrict__ trans, float* __restrict__ loss_out) {
  int tid = threadIdx.x;  // 64 threads
  float val = 0.f;
  if (tid < B_) {
    const float* e = emis + (size_t)tid * W_ * NT_;
    const int* tg = tags + (size_t)tid * W_;
    const float t00 = trans[0], t01 = trans[1], t10 = trans[2], t11 = trans[3];
    int tp = tg[0];
    float num = start[tp] + e[tp];
    float a0 = start[0] + e[0];
    float a1 = start[1] + e[1];
    for (int s = 1; s < W_; ++s) {
      int ts = tg[s];
      num += e[2 * s + ts] + trans[tp * 2 + ts];
      tp = ts;
      float n0 = lse2(a0 + t00, a1 + t10) + e[2 * s];
      float n1 = lse2(a0 + t01, a1 + t11) + e[2 * s + 1];
      a0 = n0;
      a1 = n1;
    }
    num += endv[tp];
    float logZ = lse2(a0 + endv[0], a1 + endv[1]);
    val = num - logZ;
  }
  for (int off = 32; off > 0; off >>= 1) val += __shfl_down(val, off, 64);
  if (tid == 0) loss_out[0] = -(val / (float)B_);
}

__global__ void crf_decode_kernel(const float* __restrict__ emis,
                                  const float* __restrict__ start, const float* __restrict__ endv,
                                  const float* __restrict__ trans, float* __restrict__ path_out) {
  int b = blockIdx.x * blockDim.x + threadIdx.x;
  if (b >= B_) return;
  const float* e = emis + (size_t)b * W_ * NT_;
  const float t00 = trans[0], t01 = trans[1], t10 = trans[2], t11 = trans[3];
  float s0 = start[0] + e[0];
  float s1 = start[1] + e[1];
  unsigned long long bp0[4] = {0ull, 0ull, 0ull, 0ull};
  unsigned long long bp1[4] = {0ull, 0ull, 0ull, 0ull};
  for (int s = 1; s < W_; ++s) {
    float c00 = s0 + t00, c10 = s1 + t10;  // into j=0
    float c01 = s0 + t01, c11 = s1 + t11;  // into j=1
    int b0 = (c10 > c00) ? 1 : 0;          // argmax: first wins ties
    int b1 = (c11 > c01) ? 1 : 0;
    float m0 = b0 ? c10 : c00;
    float m1 = b1 ? c11 : c01;
    int idx = s - 1;
    bp0[idx >> 6] |= ((unsigned long long)b0) << (idx & 63);
    bp1[idx >> 6] |= ((unsigned long long)b1) << (idx & 63);
    s0 = m0 + e[2 * s];
    s1 = m1 + e[2 * s + 1];
  }
  int tag = ((s1 + endv[1]) > (s0 + endv[0])) ? 1 : 0;
  path_out[(size_t)b * W_ + (W_ - 1)] = (float)tag;
  for (int s = W_ - 2; s >= 0; --s) {
    unsigned long long word = tag ? bp1[s >> 6] : bp0[s >> 6];
    tag = (int)((word >> (s & 63)) & 1ull);
    path_out[(size_t)b * W_ + s] = (float)tag;
  }
}

// ============================ launch ============================
extern "C" void kernel_launch(void* const* d_in, const int* in_sizes, int n_in,
                              void* d_out, int out_size, void* d_ws, size_t ws_size,
                              hipStream_t stream) {
  const float* bert_out = (const float*)d_in[0];
  const int* words_ids = (const int*)d_in[1];
  const int* label_detect = (const int*)d_in[2];
  const float* w_ih_l0 = (const float*)d_in[3];
  const float* w_hh_l0 = (const float*)d_in[4];
  const float* b_l0 = (const float*)d_in[5];
  const float* w_ih_l0r = (const float*)d_in[6];
  const float* w_hh_l0r = (const float*)d_in[7];
  const float* b_l0r = (const float*)d_in[8];
  const float* w_ih_l1 = (const float*)d_in[9];
  const float* w_hh_l1 = (const float*)d_in[10];
  const float* b_l1 = (const float*)d_in[11];
  const float* w_ih_l1r = (const float*)d_in[12];
  const float* w_hh_l1r = (const float*)d_in[13];
  const float* b_l1r = (const float*)d_in[14];
  const float* w_lin = (const float*)d_in[15];
  const float* b_lin = (const float*)d_in[16];
  const float* crf_start = (const float*)d_in[17];
  const float* crf_end = (const float*)d_in[18];
  const float* crf_trans = (const float*)d_in[19];

  float* out = (float*)d_out;
  float* path_out = out;               // 8000
  float* prob_out = out + B_ * W_;     // 16000
  float* loss_out = out + B_ * W_ * 3; // 1

  // Pick LSTM variant: 512 blocks / 2 per CU if the device confirms co-residency
  // (cooperative launch with 512 blocks at 1 block/CU would fail), else r9's 256.
  int occ512 = 0;
  (void)hipOccupancyMaxActiveBlocksPerMultiprocessor(&occ512, (const void*)lstm_persist512_kernel, 256, 0);
  const bool use512 = (occ512 >= 2);

  // Adaptive time-chunk size: largest C (divides 250) whose workspace fits ws_size.
  auto need = [](int c) -> size_t { return 4ull * (24733568ull + 196608ull * (size_t)c); };
  int C = 10;
  if (ws_size >= need(250)) C = 250;
  else if (ws_size >= need(125)) C = 125;
  else if (ws_size >= need(50)) C = 50;
  else if (ws_size >= need(25)) C = 25;
  const int nchunk = W_ / C;
  const size_t CBG = (size_t)C * B_ * G_;

  // workspace layout (floats):
  //   [0 .. 12.288M)         h2 region  (feat [W][B][D] aliases its first 6.144M floats)
  //   [12.288M .. 24.576M)   h1 [W][B][2H]
  //   then preA chunk, preB chunk, hbuf, cbuf, fidx, barrier area (NBAR_ uints)
  float* h2 = (float*)d_ws;
  float* feat = h2;  // alias: feat dead before h2 is written
  float* h1 = h2 + 12288000;
  float* preA = h1 + 12288000;
  float* preB = preA + CBG;
  float* hbuf = preB + CBG;
  float* cbuf = hbuf + 2 * 2 * B_ * H_;
  int* fidx = (int*)(cbuf + 2 * B_ * H_);
  unsigned int* counter = (unsigned int*)(fidx + B_ * W_);

  // 1) first-subtoken gather -> feat [W][B][D]  (also zeroes the barrier area)
  first_idx_kernel<<<(B_ * W_ + 255) / 256, 256, 0, stream>>>(words_ids, fidx, counter);
  gather_kernel<<<(B_ * W_ * (D_ / 4) + 255) / 256, 256, 0, stream>>>(bert_out, fidx, feat);

  const int Mc = C * B_;
  dim3 ggrid((Mc + 127) / 128, G_ / 128);
  int ep = 0;  // barrier epoch base (monotonic across all persistent launches)

  void* lstm_fn = use512 ? (void*)lstm_persist512_kernel : (void*)lstm_persist_kernel;
  const dim3 lstm_grid = use512 ? dim3(512) : dim3(256);

  // 2) layer 0: per chunk, fwd+rev input projections then one persistent recurrence launch
  for (int ch = 0; ch < nchunk; ++ch) {
    const int s0 = ch * C;
    gemm_bias_kernel<<<ggrid, 256, 0, stream>>>(feat + (size_t)s0 * B_ * D_, w_ih_l0, b_l0, preA, Mc, G_, D_);
    gemm_bias_kernel<<<ggrid, 256, 0, stream>>>(feat + (size_t)(W_ - C - s0) * B_ * D_, w_ih_l0r, b_l0r, preB, Mc, G_, D_);
    const float* a0 = preA; const float* a1 = preB;
    const float* a2 = w_hh_l0; const float* a3 = w_hh_l0r;
    float* a4 = h1; float* a5 = hbuf; float* a6 = cbuf;
    unsigned int* a7 = counter; int a8 = s0; int a9 = C; int a10 = ep;
    void* args[] = {&a0, &a1, &a2, &a3, &a4, &a5, &a6, &a7, &a8, &a9, &a10};
    hipLaunchCooperativeKernel(lstm_fn, lstm_grid, dim3(256), args, 0, stream);
    ep += C;
  }

  // 3) layer 1 (K = 1536)
  for (int ch = 0; ch < nchunk; ++ch) {
    const int s0 = ch * C;
    gemm_bias_kernel<<<ggrid, 256, 0, stream>>>(h1 + (size_t)s0 * B_ * (2 * H_), w_ih_l1, b_l1, preA, Mc, G_, 2 * H_);
    gemm_bias_kernel<<<ggrid, 256, 0, stream>>>(h1 + (size_t)(W_ - C - s0) * B_ * (2 * H_), w_ih_l1r, b_l1r, preB, Mc, G_, 2 * H_);
    const float* a0 = preA; const float* a1 = preB;
    const float* a2 = w_hh_l1; const float* a3 = w_hh_l1r;
    float* a4 = h2; float* a5 = hbuf; float* a6 = cbuf;
    unsigned int* a7 = counter; int a8 = s0; int a9 = C; int a10 = ep;
    void* args[] = {&a0, &a1, &a2, &a3, &a4, &a5, &a6, &a7, &a8, &a9, &a10};
    hipLaunchCooperativeKernel(lstm_fn, lstm_grid, dim3(256), args, 0, stream);
    ep += C;
  }

  // 4) logits + softmax -> ner_prob (written straight into d_out)
  logits_softmax_kernel<<<(B_ * W_ + 255) / 256, 256, 0, stream>>>(h2, w_lin, b_lin, prob_out);

  // 5) CRF log-likelihood -> loss, Viterbi decode -> path
  crf_llh_kernel<<<1, 64, 0, stream>>>(prob_out, label_detect, crf_start, crf_end, crf_trans, loss_out);
  crf_decode_kernel<<<1, 64, 0, stream>>>(prob_out, crf_start, crf_end, crf_trans, path_out);
}

// Round 11
// 10862.984 us; speedup vs baseline: 1.0018x; 1.0018x over previous
//
#include <hip/hip_runtime.h>
#include <cmath>

#define B_ 32
#define T_ 512
#define W_ 250
#define D_ 768
#define H_ 768
#define G_ 3072   // 4*H
#define NT_ 2

#define NBAR_ 2176   // barrier area: 512-variant uses 16 grp lines (2 dirs x 8), 2 root lines,
                     // 16 go lines, all 256B-separated. 256-variant uses its own subset layout.

// ============================ first-subtoken gather ============================
__global__ void first_idx_kernel(const int* __restrict__ words_ids, int* __restrict__ fidx,
                                 unsigned int* __restrict__ counter) {
  int i = blockIdx.x * blockDim.x + threadIdx.x;
  if (i < NBAR_) counter[i] = 0u;  // zero the whole barrier area
  if (i >= B_ * W_) return;
  int b = i / W_, w = i % W_;
  const int* row = words_ids + (size_t)b * T_;
  int idx = T_ - 1;
  for (int t = 0; t < T_; ++t) {
    if (row[t] == w) { idx = t; break; }
  }
  fidx[i] = idx;
}

// feat layout: [W][B][D]  (time-major so a time-chunk is contiguous GEMM rows)
__global__ void gather_kernel(const float* __restrict__ bert_out, const int* __restrict__ fidx,
                              float* __restrict__ feat) {
  int i = blockIdx.x * blockDim.x + threadIdx.x;
  const int nv = D_ / 4;
  if (i >= B_ * W_ * nv) return;
  int bw = i / nv, d4 = i % nv;
  int b = bw / W_, w = bw % W_;
  int t = fidx[bw];
  float4 v = ((const float4*)(bert_out + ((size_t)b * T_ + t) * D_))[d4];
  ((float4*)(feat + ((size_t)w * B_ + b) * D_))[d4] = v;
}

// ============================ fp32 GEMM: C[M,N] = A[M,K] * B[N,K]^T + bias[N] ============================
__global__ __launch_bounds__(256) void gemm_bias_kernel(
    const float* __restrict__ A, const float* __restrict__ Bm,
    const float* __restrict__ bias, float* __restrict__ C,
    int M, int N, int K) {
  __shared__ float As[2][16][132];
  __shared__ float Bs[2][16][132];
  const int tid = threadIdx.x;
  const int row0 = blockIdx.x * 128;
  const int col0 = blockIdx.y * 128;
  const int tx = tid & 15;       // N dim of microtile
  const int ty = tid >> 4;       // M dim of microtile
  const int lr = tid >> 1;       // 0..127 : tile row this thread loads
  const int lk = (tid & 1) * 8;  // k offset 0 or 8

  int ar = row0 + lr;
  if (ar >= M) ar = M - 1;                 // clamp (results of padded rows never stored)
  const float* __restrict__ Ap = A + (size_t)ar * K + lk;
  const float* __restrict__ Bp = Bm + (size_t)(col0 + lr) * K + lk;

  float acc[8][8];
#pragma unroll
  for (int i = 0; i < 8; ++i)
#pragma unroll
    for (int j = 0; j < 8; ++j) acc[i][j] = 0.0f;

  const int nk = K >> 4;

  {
    float4 a0 = *(const float4*)(Ap + 0);
    float4 a1 = *(const float4*)(Ap + 4);
    float4 b0 = *(const float4*)(Bp + 0);
    float4 b1 = *(const float4*)(Bp + 4);
    As[0][lk + 0][lr] = a0.x; As[0][lk + 1][lr] = a0.y; As[0][lk + 2][lr] = a0.z; As[0][lk + 3][lr] = a0.w;
    As[0][lk + 4][lr] = a1.x; As[0][lk + 5][lr] = a1.y; As[0][lk + 6][lr] = a1.z; As[0][lk + 7][lr] = a1.w;
    Bs[0][lk + 0][lr] = b0.x; Bs[0][lk + 1][lr] = b0.y; Bs[0][lk + 2][lr] = b0.z; Bs[0][lk + 3][lr] = b0.w;
    Bs[0][lk + 4][lr] = b1.x; Bs[0][lk + 5][lr] = b1.y; Bs[0][lk + 6][lr] = b1.z; Bs[0][lk + 7][lr] = b1.w;
  }
  __syncthreads();

  for (int t = 0; t < nk; ++t) {
    const int cur = t & 1;
    float4 a0, a1, b0, b1;
    const bool pf = (t + 1 < nk);
    if (pf) {
      const int k0 = (t + 1) << 4;
      a0 = *(const float4*)(Ap + k0);
      a1 = *(const float4*)(Ap + k0 + 4);
      b0 = *(const float4*)(Bp + k0);
      b1 = *(const float4*)(Bp + k0 + 4);
    }
#pragma unroll
    for (int k = 0; k < 16; ++k) {
      float a[8], b[8];
      *(float4*)&a[0] = *(const float4*)&As[cur][k][ty * 8];
      *(float4*)&a[4] = *(const float4*)&As[cur][k][ty * 8 + 4];
      *(float4*)&b[0] = *(const float4*)&Bs[cur][k][tx * 8];
      *(float4*)&b[4] = *(const float4*)&Bs[cur][k][tx * 8 + 4];
#pragma unroll
      for (int i = 0; i < 8; ++i)
#pragma unroll
        for (int j = 0; j < 8; ++j) acc[i][j] += a[i] * b[j];
    }
    if (pf) {
      const int nxt = cur ^ 1;
      As[nxt][lk + 0][lr] = a0.x; As[nxt][lk + 1][lr] = a0.y; As[nxt][lk + 2][lr] = a0.z; As[nxt][lk + 3][lr] = a0.w;
      As[nxt][lk + 4][lr] = a1.x; As[nxt][lk + 5][lr] = a1.y; As[nxt][lk + 6][lr] = a1.z; As[nxt][lk + 7][lr] = a1.w;
      Bs[nxt][lk + 0][lr] = b0.x; Bs[nxt][lk + 1][lr] = b0.y; Bs[nxt][lk + 2][lr] = b0.z; Bs[nxt][lk + 3][lr] = b0.w;
      Bs[nxt][lk + 4][lr] = b1.x; Bs[nxt][lk + 5][lr] = b1.y; Bs[nxt][lk + 6][lr] = b1.z; Bs[nxt][lk + 7][lr] = b1.w;
    }
    __syncthreads();
  }

#pragma unroll
  for (int i = 0; i < 8; ++i) {
    int r = row0 + ty * 8 + i;
    if (r < M) {
#pragma unroll
      for (int j = 0; j < 8; ++j) {
        int c = col0 + tx * 8 + j;
        C[(size_t)r * N + c] = acc[i][j] + bias[c];
      }
    }
  }
}

// ============================ BiLSTM recurrence: PERSISTENT, 256 blocks (r9, proven) ============================
// Fallback variant. 256 blocks x 6 units, 1 block/CU. Identical to round 9's passing kernel.
__global__ __launch_bounds__(256) void lstm_persist_kernel(
    const float* __restrict__ pre_f, const float* __restrict__ pre_r,
    const float* __restrict__ whh_f, const float* __restrict__ whh_r,
    float* __restrict__ out, float* __restrict__ hbuf, float* __restrict__ cbuf,
    unsigned int* __restrict__ counter, int s0, int Cc, int ep0) {
  const int wg = blockIdx.x;
  const int dir = wg >> 7;
  const int lw = wg & 127;
  const float* __restrict__ pre = dir ? pre_r : pre_f;
  const float* __restrict__ whh = dir ? whh_r : whh_f;
  float* hb = hbuf + (size_t)dir * 2 * B_ * H_;
  float* cb = cbuf + (size_t)dir * B_ * H_;
  const int tid = threadIdx.x;
  const int u0 = lw * 6;

  const int rgrp = tid >> 6;
  const int lane = tid & 63;
  const int kgrp = lane >> 3;
  const int bgrp = lane & 7;

  __shared__ float w_lds[24 * 860];
  __shared__ float h_lds[32 * 284];
  __shared__ float g_lds[32][24];

  unsigned int* __restrict__ grp  = counter + ((wg & 7) << 6);
  unsigned int* __restrict__ root = counter + 512;
  unsigned int* __restrict__ gow  = counter + 576 + ((wg & 7) << 6);

#pragma unroll
  for (int v = 0; v < 18; ++v) {
    int i = v * 256 + tid;
    int r24 = i / 192;
    int f4 = i - r24 * 192;
    int k = f4 * 4;
    int grow = (r24 / 6) * H_ + u0 + (r24 % 6);
    *(float4*)&w_lds[r24 * 860 + k + 4 * (k >> 5)] =
        *(const float4*)(whh + (size_t)grow * H_ + k);
  }

  const int cui = tid >> 5;
  const int cb_ = tid & 31;
  float creg = 0.0f;
  if (tid < 192 && s0 > 0) creg = cb[(size_t)cb_ * H_ + u0 + cui];

  float pre_g0 = 0.f, pre_g1 = 0.f, pre_g2 = 0.f, pre_g3 = 0.f;
  if (tid < 192) {
    const int prow0 = dir ? (Cc - 1) : 0;
    const float* pbt = pre + ((size_t)prow0 * B_ + cb_) * G_;
    pre_g0 = pbt[0 * H_ + u0 + cui];
    pre_g1 = pbt[1 * H_ + u0 + cui];
    pre_g2 = pbt[2 * H_ + u0 + cui];
    pre_g3 = pbt[3 * H_ + u0 + cui];
  }

  const int kl0 = kgrp * 32;

  for (int sl = 0; sl < Cc; ++sl) {
    const int s = s0 + sl;
    const int w = dir ? (W_ - 1 - s) : s;

    float acc[6][4];
#pragma unroll
    for (int r = 0; r < 6; ++r)
#pragma unroll
      for (int j = 0; j < 4; ++j) acc[r][j] = 0.0f;

    if (s > 0) {
      const float* __restrict__ hprev = hb + (size_t)(s & 1) * B_ * H_;

      unsigned long long hq[16];
#pragma unroll
      for (int v = 0; v < 8; ++v) {
        int e = v * 1024 + tid * 4;
        int bb = e >> 8;
        int kk = e & 255;
        const unsigned long long* src =
            (const unsigned long long*)(hprev + (size_t)bb * H_ + kk);
        hq[2 * v]     = __hip_atomic_load(src + 0, __ATOMIC_RELAXED, __HIP_MEMORY_SCOPE_AGENT);
        hq[2 * v + 1] = __hip_atomic_load(src + 1, __ATOMIC_RELAXED, __HIP_MEMORY_SCOPE_AGENT);
      }

      for (int kc = 0; kc < H_; kc += 256) {
        __syncthreads();
#pragma unroll
        for (int v = 0; v < 8; ++v) {
          int e = v * 1024 + tid * 4;
          int bb = e >> 8;
          int kk = e & 255;
          int off = bb * 284 + kk + 4 * (kk >> 5);
          union { unsigned long long u; float f[2]; } q0, q1;
          q0.u = hq[2 * v]; q1.u = hq[2 * v + 1];
          h_lds[off + 0] = q0.f[0]; h_lds[off + 1] = q0.f[1];
          h_lds[off + 2] = q1.f[0]; h_lds[off + 3] = q1.f[1];
        }
        __syncthreads();
        if (kc + 256 < H_) {
#pragma unroll
          for (int v = 0; v < 8; ++v) {
            int e = v * 1024 + tid * 4;
            int bb = e >> 8;
            int kk = e & 255;
            const unsigned long long* src =
                (const unsigned long long*)(hprev + (size_t)bb * H_ + kc + 256 + kk);
            hq[2 * v]     = __hip_atomic_load(src + 0, __ATOMIC_RELAXED, __HIP_MEMORY_SCOPE_AGENT);
            hq[2 * v + 1] = __hip_atomic_load(src + 1, __ATOMIC_RELAXED, __HIP_MEMORY_SCOPE_AGENT);
          }
        }

        const int wbase = kc + kl0;
#pragma unroll 4
        for (int t = 0; t < 8; ++t) {
          const int kl = kl0 + t * 4;
          const int ka = wbase + t * 4;
          const int hoff = kl + 4 * (kl >> 5);
          const int woff = ka + 4 * (ka >> 5);
          float4 h4_0 = *(const float4*)&h_lds[(4 * bgrp + 0) * 284 + hoff];
          float4 h4_1 = *(const float4*)&h_lds[(4 * bgrp + 1) * 284 + hoff];
          float4 h4_2 = *(const float4*)&h_lds[(4 * bgrp + 2) * 284 + hoff];
          float4 h4_3 = *(const float4*)&h_lds[(4 * bgrp + 3) * 284 + hoff];
#pragma unroll
          for (int r = 0; r < 6; ++r) {
            float4 w4 = *(const float4*)&w_lds[(rgrp * 6 + r) * 860 + woff];
            acc[r][0] += h4_0.x * w4.x + h4_0.y * w4.y + h4_0.z * w4.z + h4_0.w * w4.w;
            acc[r][1] += h4_1.x * w4.x + h4_1.y * w4.y + h4_1.z * w4.z + h4_1.w * w4.w;
            acc[r][2] += h4_2.x * w4.x + h4_2.y * w4.y + h4_2.z * w4.z + h4_2.w * w4.w;
            acc[r][3] += h4_3.x * w4.x + h4_3.y * w4.y + h4_3.z * w4.z + h4_3.w * w4.w;
          }
        }
      }

#pragma unroll
      for (int r = 0; r < 6; ++r)
#pragma unroll
        for (int j = 0; j < 4; ++j) {
          float a = acc[r][j];
          a += __shfl_xor(a, 8, 64);
          a += __shfl_xor(a, 16, 64);
          a += __shfl_xor(a, 32, 64);
          acc[r][j] = a;
        }
      if (kgrp == 0) {
#pragma unroll
        for (int r = 0; r < 6; ++r)
#pragma unroll
          for (int j = 0; j < 4; ++j)
            g_lds[4 * bgrp + j][rgrp * 6 + r] = acc[r][j];
      }
    }

    __syncthreads();

    if (tid < 192) {
      float gi = pre_g0, gf = pre_g1, gg = pre_g2, go = pre_g3;
      if (s > 0) {
        gi += g_lds[cb_][cui];
        gf += g_lds[cb_][6 + cui];
        gg += g_lds[cb_][12 + cui];
        go += g_lds[cb_][18 + cui];
      }
      const float si = 1.0f / (1.0f + expf(-gi));
      const float sf = 1.0f / (1.0f + expf(-gf));
      const float so = 1.0f / (1.0f + expf(-go));
      creg = sf * creg + si * tanhf(gg);
      const float h = so * tanhf(creg);
      float* __restrict__ hnext = hb + (size_t)((s + 1) & 1) * B_ * H_;
      __hip_atomic_store(&hnext[(size_t)cb_ * H_ + u0 + cui], h,
                         __ATOMIC_RELAXED, __HIP_MEMORY_SCOPE_AGENT);
      out[((size_t)w * B_ + cb_) * (2 * H_) + (size_t)dir * H_ + u0 + cui] = h;
      if (sl + 1 < Cc) {
        const int prown = dir ? (Cc - 2 - sl) : (sl + 1);
        const float* pbtn = pre + ((size_t)prown * B_ + cb_) * G_;
        pre_g0 = pbtn[0 * H_ + u0 + cui];
        pre_g1 = pbtn[1 * H_ + u0 + cui];
        pre_g2 = pbtn[2 * H_ + u0 + cui];
        pre_g3 = pbtn[3 * H_ + u0 + cui];
      }
    }

    __syncthreads();
    if (tid == 0) {
      const unsigned int ep1 = (unsigned int)(ep0 + sl + 1);
      unsigned int old = __hip_atomic_fetch_add(grp, 1u, __ATOMIC_RELAXED, __HIP_MEMORY_SCOPE_AGENT);
      if (old == 32u * ep1 - 1u) {
        __hip_atomic_fetch_add(root, 1u, __ATOMIC_RELAXED, __HIP_MEMORY_SCOPE_AGENT);
        while (__hip_atomic_load(root, __ATOMIC_RELAXED, __HIP_MEMORY_SCOPE_AGENT) < 8u * ep1) {
          __builtin_amdgcn_s_sleep(2);
        }
        __hip_atomic_store(gow, ep1, __ATOMIC_RELAXED, __HIP_MEMORY_SCOPE_AGENT);
      } else {
        while (__hip_atomic_load(gow, __ATOMIC_RELAXED, __HIP_MEMORY_SCOPE_AGENT) < ep1) {
          __builtin_amdgcn_s_sleep(2);
        }
      }
    }
    __syncthreads();
  }

  if (tid < 192) cb[(size_t)cb_ * H_ + u0 + cui] = creg;
}

// ============================ BiLSTM recurrence: PERSISTENT, 512 blocks / 2 per CU ============================
// ROUND 11: r10's 512-block kernel with the barrier SPLIT PER DIRECTION. fwd and rev
// LSTMs are fully independent (disjoint hb/cb/pre/out), so each direction runs its own
// 256-block two-level barrier (r7's proven algorithm on disjoint 256B-separated lines:
// 8 groups x 32 arrivals, root to 8*ep, per-group go release). With dir = wg>>8,
// block i (fwd) and i+256 (rev) land on the same XCD/CU slot (256 % 8 == 0 under
// round-robin dispatch), so one direction's barrier wait + staging latency hides under
// its CU-mate's FMA phase - r10's single shared barrier made both co-resident blocks
// spin simultaneously, which is why doubling occupancy was time-neutral.
// Data path byte-identical to r10's passing 512 kernel -> absmax 0.0.
__global__ __launch_bounds__(256) void lstm_persist512_kernel(
    const float* __restrict__ pre_f, const float* __restrict__ pre_r,
    const float* __restrict__ whh_f, const float* __restrict__ whh_r,
    float* __restrict__ out, float* __restrict__ hbuf, float* __restrict__ cbuf,
    unsigned int* __restrict__ counter, int s0, int Cc, int ep0) {
  const int wg = blockIdx.x;
  const int dir = wg >> 8;         // 512 blocks: 256 per direction; i and i+256 share a CU
  const int lw = wg & 255;
  const float* __restrict__ pre = dir ? pre_r : pre_f;
  const float* __restrict__ whh = dir ? whh_r : whh_f;
  float* hb = hbuf + (size_t)dir * 2 * B_ * H_;
  float* cb = cbuf + (size_t)dir * B_ * H_;
  const int tid = threadIdx.x;
  const int u0 = lw * 3;           // 3 units per block

  const int rgrp = tid >> 6;       // wave index == gate 0..3
  const int lane = tid & 63;
  const int kgrp = lane >> 3;      // 0..7 : k-split
  const int bgrp = lane & 7;       // 0..7 : batch quad

  __shared__ float w_lds[12 * 860];   // 41280 B, skewed: this block's 12 gate rows
  __shared__ float h_lds[32 * 284];   // 36352 B, skewed, one 256-k chunk
  __shared__ float g_lds[32][12];     // 1536 B

  // per-direction barrier lines: grp dir0 at 0..448, dir1 at 512..960;
  // root dir0 at 1024, dir1 at 1088; go dir0 at 1152.., dir1 at 1664..
  const int grpIdx = lw & 7;       // 8 groups x 32 blocks per direction
  unsigned int* __restrict__ grp  = counter + ((dir * 8 + grpIdx) << 6);
  unsigned int* __restrict__ root = counter + 1024 + (dir << 6);
  unsigned int* __restrict__ gow  = counter + 1152 + ((dir * 8 + grpIdx) << 6);

  // ---- stage 12 weight rows into skewed LDS ONCE (2304 float4, 9/thread) ----
#pragma unroll
  for (int v = 0; v < 9; ++v) {
    int i = v * 256 + tid;          // 0..2303
    int r12 = i / 192;              // 0..11
    int f4 = i - r12 * 192;         // 0..191
    int k = f4 * 4;
    int grow = (r12 / 3) * H_ + u0 + (r12 % 3);
    *(float4*)&w_lds[r12 * 860 + k + 4 * (k >> 5)] =
        *(const float4*)(whh + (size_t)grow * H_ + k);
  }

  // combine-thread ownership: tid<96 owns (batch cb_, unit cui); c kept in register
  const int cui = tid >> 5;        // 0..2 valid when tid < 96
  const int cb_ = tid & 31;
  float creg = 0.0f;
  if (tid < 96 && s0 > 0) creg = cb[(size_t)cb_ * H_ + u0 + cui];

  float pre_g0 = 0.f, pre_g1 = 0.f, pre_g2 = 0.f, pre_g3 = 0.f;
  if (tid < 96) {
    const int prow0 = dir ? (Cc - 1) : 0;
    const float* pbt = pre + ((size_t)prow0 * B_ + cb_) * G_;
    pre_g0 = pbt[0 * H_ + u0 + cui];
    pre_g1 = pbt[1 * H_ + u0 + cui];
    pre_g2 = pbt[2 * H_ + u0 + cui];
    pre_g3 = pbt[3 * H_ + u0 + cui];
  }

  const int kl0 = kgrp * 32;

  for (int sl = 0; sl < Cc; ++sl) {
    const int s = s0 + sl;
    const int w = dir ? (W_ - 1 - s) : s;

    float acc[3][4];
#pragma unroll
    for (int r = 0; r < 3; ++r)
#pragma unroll
      for (int j = 0; j < 4; ++j) acc[r][j] = 0.0f;

    if (s > 0) {
      const float* __restrict__ hprev = hb + (size_t)(s & 1) * B_ * H_;

      unsigned long long hq[16];
#pragma unroll
      for (int v = 0; v < 8; ++v) {
        int e = v * 1024 + tid * 4;
        int bb = e >> 8;
        int kk = e & 255;
        const unsigned long long* src =
            (const unsigned long long*)(hprev + (size_t)bb * H_ + kk);
        hq[2 * v]     = __hip_atomic_load(src + 0, __ATOMIC_RELAXED, __HIP_MEMORY_SCOPE_AGENT);
        hq[2 * v + 1] = __hip_atomic_load(src + 1, __ATOMIC_RELAXED, __HIP_MEMORY_SCOPE_AGENT);
      }

      for (int kc = 0; kc < H_; kc += 256) {
        __syncthreads();
#pragma unroll
        for (int v = 0; v < 8; ++v) {
          int e = v * 1024 + tid * 4;
          int bb = e >> 8;
          int kk = e & 255;
          int off = bb * 284 + kk + 4 * (kk >> 5);
          union { unsigned long long u; float f[2]; } q0, q1;
          q0.u = hq[2 * v]; q1.u = hq[2 * v + 1];
          h_lds[off + 0] = q0.f[0]; h_lds[off + 1] = q0.f[1];
          h_lds[off + 2] = q1.f[0]; h_lds[off + 3] = q1.f[1];
        }
        __syncthreads();
        if (kc + 256 < H_) {
#pragma unroll
          for (int v = 0; v < 8; ++v) {
            int e = v * 1024 + tid * 4;
            int bb = e >> 8;
            int kk = e & 255;
            const unsigned long long* src =
                (const unsigned long long*)(hprev + (size_t)bb * H_ + kc + 256 + kk);
            hq[2 * v]     = __hip_atomic_load(src + 0, __ATOMIC_RELAXED, __HIP_MEMORY_SCOPE_AGENT);
            hq[2 * v + 1] = __hip_atomic_load(src + 1, __ATOMIC_RELAXED, __HIP_MEMORY_SCOPE_AGENT);
          }
        }

        const int wbase = kc + kl0;
#pragma unroll 4
        for (int t = 0; t < 8; ++t) {
          const int kl = kl0 + t * 4;
          const int ka = wbase + t * 4;
          const int hoff = kl + 4 * (kl >> 5);
          const int woff = ka + 4 * (ka >> 5);
          float4 h4_0 = *(const float4*)&h_lds[(4 * bgrp + 0) * 284 + hoff];
          float4 h4_1 = *(const float4*)&h_lds[(4 * bgrp + 1) * 284 + hoff];
          float4 h4_2 = *(const float4*)&h_lds[(4 * bgrp + 2) * 284 + hoff];
          float4 h4_3 = *(const float4*)&h_lds[(4 * bgrp + 3) * 284 + hoff];
#pragma unroll
          for (int r = 0; r < 3; ++r) {
            float4 w4 = *(const float4*)&w_lds[(rgrp * 3 + r) * 860 + woff];
            acc[r][0] += h4_0.x * w4.x + h4_0.y * w4.y + h4_0.z * w4.z + h4_0.w * w4.w;
            acc[r][1] += h4_1.x * w4.x + h4_1.y * w4.y + h4_1.z * w4.z + h4_1.w * w4.w;
            acc[r][2] += h4_2.x * w4.x + h4_2.y * w4.y + h4_2.z * w4.z + h4_2.w * w4.w;
            acc[r][3] += h4_3.x * w4.x + h4_3.y * w4.y + h4_3.z * w4.z + h4_3.w * w4.w;
          }
        }
      }

#pragma unroll
      for (int r = 0; r < 3; ++r)
#pragma unroll
        for (int j = 0; j < 4; ++j) {
          float a = acc[r][j];
          a += __shfl_xor(a, 8, 64);
          a += __shfl_xor(a, 16, 64);
          a += __shfl_xor(a, 32, 64);
          acc[r][j] = a;
        }
      if (kgrp == 0) {
#pragma unroll
        for (int r = 0; r < 3; ++r)
#pragma unroll
          for (int j = 0; j < 4; ++j)
            g_lds[4 * bgrp + j][rgrp * 3 + r] = acc[r][j];
      }
    }

    __syncthreads();

    if (tid < 96) {
      float gi = pre_g0, gf = pre_g1, gg = pre_g2, go = pre_g3;
      if (s > 0) {
        gi += g_lds[cb_][cui];
        gf += g_lds[cb_][3 + cui];
        gg += g_lds[cb_][6 + cui];
        go += g_lds[cb_][9 + cui];
      }
      const float si = 1.0f / (1.0f + expf(-gi));
      const float sf = 1.0f / (1.0f + expf(-gf));
      const float so = 1.0f / (1.0f + expf(-go));
      creg = sf * creg + si * tanhf(gg);
      const float h = so * tanhf(creg);
      float* __restrict__ hnext = hb + (size_t)((s + 1) & 1) * B_ * H_;
      __hip_atomic_store(&hnext[(size_t)cb_ * H_ + u0 + cui], h,
                         __ATOMIC_RELAXED, __HIP_MEMORY_SCOPE_AGENT);
      out[((size_t)w * B_ + cb_) * (2 * H_) + (size_t)dir * H_ + u0 + cui] = h;
      if (sl + 1 < Cc) {
        const int prown = dir ? (Cc - 2 - sl) : (sl + 1);
        const float* pbtn = pre + ((size_t)prown * B_ + cb_) * G_;
        pre_g0 = pbtn[0 * H_ + u0 + cui];
        pre_g1 = pbtn[1 * H_ + u0 + cui];
        pre_g2 = pbtn[2 * H_ + u0 + cui];
        pre_g3 = pbtn[3 * H_ + u0 + cui];
      }
    }

    // ---- per-direction two-level barrier (r7 algorithm, 8 groups x 32 blocks per dir) ----
    __syncthreads();
    if (tid == 0) {
      const unsigned int ep1 = (unsigned int)(ep0 + sl + 1);
      unsigned int old = __hip_atomic_fetch_add(grp, 1u, __ATOMIC_RELAXED, __HIP_MEMORY_SCOPE_AGENT);
      if (old == 32u * ep1 - 1u) {
        __hip_atomic_fetch_add(root, 1u, __ATOMIC_RELAXED, __HIP_MEMORY_SCOPE_AGENT);
        while (__hip_atomic_load(root, __ATOMIC_RELAXED, __HIP_MEMORY_SCOPE_AGENT) < 8u * ep1) {
          __builtin_amdgcn_s_sleep(2);
        }
        __hip_atomic_store(gow, ep1, __ATOMIC_RELAXED, __HIP_MEMORY_SCOPE_AGENT);
      } else {
        while (__hip_atomic_load(gow, __ATOMIC_RELAXED, __HIP_MEMORY_SCOPE_AGENT) < ep1) {
          __builtin_amdgcn_s_sleep(2);
        }
      }
    }
    __syncthreads();
  }

  if (tid < 96) cb[(size_t)cb_ * H_ + u0 + cui] = creg;
}

// ============================ logits + softmax ============================
// h2 is [W][B][2H]; prob is [B][W][NT]
__global__ void logits_softmax_kernel(const float* __restrict__ h2, const float* __restrict__ w_lin,
                                      const float* __restrict__ b_lin, float* __restrict__ prob) {
  int i = blockIdx.x * blockDim.x + threadIdx.x;
  if (i >= B_ * W_) return;
  int b = i / W_, w = i % W_;
  const float4* x = (const float4*)(h2 + ((size_t)w * B_ + b) * (2 * H_));
  const float4* w0 = (const float4*)(w_lin);
  const float4* w1 = (const float4*)(w_lin + 2 * H_);
  float l0 = 0.f, l1 = 0.f;
#pragma unroll 4
  for (int k = 0; k < (2 * H_) / 4; ++k) {
    float4 xv = x[k];
    float4 a = w0[k];
    float4 c = w1[k];
    l0 += xv.x * a.x + xv.y * a.y + xv.z * a.z + xv.w * a.w;
    l1 += xv.x * c.x + xv.y * c.y + xv.z * c.z + xv.w * c.w;
  }
  l0 += b_lin[0];
  l1 += b_lin[1];
  float m = fmaxf(l0, l1);
  float e0 = expf(l0 - m), e1 = expf(l1 - m);
  float s = e0 + e1;
  prob[2 * (size_t)i] = e0 / s;
  prob[2 * (size_t)i + 1] = e1 / s;
}

// ============================ CRF ============================
__device__ __forceinline__ float lse2(float a, float b) {
  float m = fmaxf(a, b);
  return m + logf(expf(a - m) + expf(b - m));
}

__global__ void crf_llh_kernel(const float* __restrict__ emis, const int* __restrict__ tags,
                               const float* __restrict__ start, const float* __restrict__ endv,
                               const float* __restrict__ trans, float* __restrict__ loss_out) {
  int tid = threadIdx.x;  // 64 threads
  float val = 0.f;
  if (tid < B_) {
    const float* e = emis + (size_t)tid * W_ * NT_;
    const int* tg = tags + (size_t)tid * W_;
    const float t00 = trans[0], t01 = trans[1], t10 = trans[2], t11 = trans[3];
    int tp = tg[0];
    float num = start[tp] + e[tp];
    float a0 = start[0] + e[0];
    float a1 = start[1] + e[1];
    for (int s = 1; s < W_; ++s) {
      int ts = tg[s];
      num += e[2 * s + ts] + trans[tp * 2 + ts];
      tp = ts;
      float n0 = lse2(a0 + t00, a1 + t10) + e[2 * s];
      float n1 = lse2(a0 + t01, a1 + t11) + e[2 * s + 1];
      a0 = n0;
      a1 = n1;
    }
    num += endv[tp];
    float logZ = lse2(a0 + endv[0], a1 + endv[1]);
    val = num - logZ;
  }
  for (int off = 32; off > 0; off >>= 1) val += __shfl_down(val, off, 64);
  if (tid == 0) loss_out[0] = -(val / (float)B_);
}

__global__ void crf_decode_kernel(const float* __restrict__ emis,
                                  const float* __restrict__ start, const float* __restrict__ endv,
                                  const float* __restrict__ trans, float* __restrict__ path_out) {
  int b = blockIdx.x * blockDim.x + threadIdx.x;
  if (b >= B_) return;
  const float* e = emis + (size_t)b * W_ * NT_;
  const float t00 = trans[0], t01 = trans[1], t10 = trans[2], t11 = trans[3];
  float s0 = start[0] + e[0];
  float s1 = start[1] + e[1];
  unsigned long long bp0[4] = {0ull, 0ull, 0ull, 0ull};
  unsigned long long bp1[4] = {0ull, 0ull, 0ull, 0ull};
  for (int s = 1; s < W_; ++s) {
    float c00 = s0 + t00, c10 = s1 + t10;  // into j=0
    float c01 = s0 + t01, c11 = s1 + t11;  // into j=1
    int b0 = (c10 > c00) ? 1 : 0;          // argmax: first wins ties
    int b1 = (c11 > c01) ? 1 : 0;
    float m0 = b0 ? c10 : c00;
    float m1 = b1 ? c11 : c01;
    int idx = s - 1;
    bp0[idx >> 6] |= ((unsigned long long)b0) << (idx & 63);
    bp1[idx >> 6] |= ((unsigned long long)b1) << (idx & 63);
    s0 = m0 + e[2 * s];
    s1 = m1 + e[2 * s + 1];
  }
  int tag = ((s1 + endv[1]) > (s0 + endv[0])) ? 1 : 0;
  path_out[(size_t)b * W_ + (W_ - 1)] = (float)tag;
  for (int s = W_ - 2; s >= 0; --s) {
    unsigned long long word = tag ? bp1[s >> 6] : bp0[s >> 6];
    tag = (int)((word >> (s & 63)) & 1ull);
    path_out[(size_t)b * W_ + s] = (float)tag;
  }
}

// ============================ launch ============================
extern "C" void kernel_launch(void* const* d_in, const int* in_sizes, int n_in,
                              void* d_out, int out_size, void* d_ws, size_t ws_size,
                              hipStream_t stream) {
  const float* bert_out = (const float*)d_in[0];
  const int* words_ids = (const int*)d_in[1];
  const int* label_detect = (const int*)d_in[2];
  const float* w_ih_l0 = (const float*)d_in[3];
  const float* w_hh_l0 = (const float*)d_in[4];
  const float* b_l0 = (const float*)d_in[5];
  const float* w_ih_l0r = (const float*)d_in[6];
  const float* w_hh_l0r = (const float*)d_in[7];
  const float* b_l0r = (const float*)d_in[8];
  const float* w_ih_l1 = (const float*)d_in[9];
  const float* w_hh_l1 = (const float*)d_in[10];
  const float* b_l1 = (const float*)d_in[11];
  const float* w_ih_l1r = (const float*)d_in[12];
  const float* w_hh_l1r = (const float*)d_in[13];
  const float* b_l1r = (const float*)d_in[14];
  const float* w_lin = (const float*)d_in[15];
  const float* b_lin = (const float*)d_in[16];
  const float* crf_start = (const float*)d_in[17];
  const float* crf_end = (const float*)d_in[18];
  const float* crf_trans = (const float*)d_in[19];

  float* out = (float*)d_out;
  float* path_out = out;               // 8000
  float* prob_out = out + B_ * W_;     // 16000
  float* loss_out = out + B_ * W_ * 3; // 1

  // Pick LSTM variant: 512 blocks / 2 per CU if the device confirms co-residency,
  // else r9's proven 256-block kernel.
  int occ512 = 0;
  (void)hipOccupancyMaxActiveBlocksPerMultiprocessor(&occ512, (const void*)lstm_persist512_kernel, 256, 0);
  const bool use512 = (occ512 >= 2);

  // Adaptive time-chunk size: largest C (divides 250) whose workspace fits ws_size.
  auto need = [](int c) -> size_t { return 4ull * (24733632ull + 196608ull * (size_t)c); };
  int C = 10;
  if (ws_size >= need(250)) C = 250;
  else if (ws_size >= need(125)) C = 125;
  else if (ws_size >= need(50)) C = 50;
  else if (ws_size >= need(25)) C = 25;
  const int nchunk = W_ / C;
  const size_t CBG = (size_t)C * B_ * G_;

  // workspace layout (floats):
  //   [0 .. 12.288M)         h2 region  (feat [W][B][D] aliases its first 6.144M floats)
  //   [12.288M .. 24.576M)   h1 [W][B][2H]
  //   then preA chunk, preB chunk, hbuf, cbuf, fidx, barrier area (NBAR_ uints)
  float* h2 = (float*)d_ws;
  float* feat = h2;  // alias: feat dead before h2 is written
  float* h1 = h2 + 12288000;
  float* preA = h1 + 12288000;
  float* preB = preA + CBG;
  float* hbuf = preB + CBG;
  float* cbuf = hbuf + 2 * 2 * B_ * H_;
  int* fidx = (int*)(cbuf + 2 * B_ * H_);
  unsigned int* counter = (unsigned int*)(fidx + B_ * W_);

  // 1) first-subtoken gather -> feat [W][B][D]  (also zeroes the barrier area)
  first_idx_kernel<<<(B_ * W_ + 255) / 256, 256, 0, stream>>>(words_ids, fidx, counter);
  gather_kernel<<<(B_ * W_ * (D_ / 4) + 255) / 256, 256, 0, stream>>>(bert_out, fidx, feat);

  const int Mc = C * B_;
  dim3 ggrid((Mc + 127) / 128, G_ / 128);
  int ep = 0;  // barrier epoch base (monotonic across all persistent launches)

  void* lstm_fn = use512 ? (void*)lstm_persist512_kernel : (void*)lstm_persist_kernel;
  const dim3 lstm_grid = use512 ? dim3(512) : dim3(256);

  // 2) layer 0: per chunk, fwd+rev input projections then one persistent recurrence launch
  for (int ch = 0; ch < nchunk; ++ch) {
    const int s0 = ch * C;
    gemm_bias_kernel<<<ggrid, 256, 0, stream>>>(feat + (size_t)s0 * B_ * D_, w_ih_l0, b_l0, preA, Mc, G_, D_);
    gemm_bias_kernel<<<ggrid, 256, 0, stream>>>(feat + (size_t)(W_ - C - s0) * B_ * D_, w_ih_l0r, b_l0r, preB, Mc, G_, D_);
    const float* a0 = preA; const float* a1 = preB;
    const float* a2 = w_hh_l0; const float* a3 = w_hh_l0r;
    float* a4 = h1; float* a5 = hbuf; float* a6 = cbuf;
    unsigned int* a7 = counter; int a8 = s0; int a9 = C; int a10 = ep;
    void* args[] = {&a0, &a1, &a2, &a3, &a4, &a5, &a6, &a7, &a8, &a9, &a10};
    hipLaunchCooperativeKernel(lstm_fn, lstm_grid, dim3(256), args, 0, stream);
    ep += C;
  }

  // 3) layer 1 (K = 1536)
  for (int ch = 0; ch < nchunk; ++ch) {
    const int s0 = ch * C;
    gemm_bias_kernel<<<ggrid, 256, 0, stream>>>(h1 + (size_t)s0 * B_ * (2 * H_), w_ih_l1, b_l1, preA, Mc, G_, 2 * H_);
    gemm_bias_kernel<<<ggrid, 256, 0, stream>>>(h1 + (size_t)(W_ - C - s0) * B_ * (2 * H_), w_ih_l1r, b_l1r, preB, Mc, G_, 2 * H_);
    const float* a0 = preA; const float* a1 = preB;
    const float* a2 = w_hh_l1; const float* a3 = w_hh_l1r;
    float* a4 = h2; float* a5 = hbuf; float* a6 = cbuf;
    unsigned int* a7 = counter; int a8 = s0; int a9 = C; int a10 = ep;
    void* args[] = {&a0, &a1, &a2, &a3, &a4, &a5, &a6, &a7, &a8, &a9, &a10};
    hipLaunchCooperativeKernel(lstm_fn, lstm_grid, dim3(256), args, 0, stream);
    ep += C;
  }

  // 4) logits + softmax -> ner_prob (written straight into d_out)
  logits_softmax_kernel<<<(B_ * W_ + 255) / 256, 256, 0, stream>>>(h2, w_lin, b_lin, prob_out);

  // 5) CRF log-likelihood -> loss, Viterbi decode -> path
  crf_llh_kernel<<<1, 64, 0, stream>>>(prob_out, label_detect, crf_start, crf_end, crf_trans, loss_out);
  crf_decode_kernel<<<1, 64, 0, stream>>>(prob_out, crf_start, crf_end, crf_trans, path_out);
}